// Round 16
// baseline (23.737 us; speedup 1.0000x reference)
//
#include <hip/hip_runtime.h>
#include <cmath>

// Problem constants
#define BATCH 64
#define SEQLEN 512
#define NFEAT 64
#define NPATCH 125
#define PREDLEN 96
#define NCOLS 500

#define MG 8         // m-rows per block (R9 sweet spot)
#define XROW 528     // xh row length (ushorts): 512 + 16 zero tail
#define ELD 520      // enc LDS row stride (ushorts)

typedef __attribute__((ext_vector_type(8))) short short8;     // 8 bf16 (4 VGPR)
typedef __attribute__((ext_vector_type(4))) short short4v;    // 4 bf16
typedef __attribute__((ext_vector_type(4))) unsigned short ushort4v;
typedef __attribute__((ext_vector_type(4))) float f32x4;      // 16x16 acc
typedef __attribute__((ext_vector_type(16))) float f32x16;    // 32x32 acc

__device__ __forceinline__ unsigned short f2bf(float f) {   // f32 -> bf16 RNE
    unsigned int u = __float_as_uint(f);
    u += 0x7FFFu + ((u >> 16) & 1u);
    return (unsigned short)(u >> 16);
}
__device__ __forceinline__ float bf2f(unsigned short h) {
    return __uint_as_float(((unsigned int)h) << 16);
}
// 2x f32 -> packed 2x bf16 (RNE): d.lo = bf16(a), d.hi = bf16(b)
__device__ __forceinline__ unsigned int cvtpk(float a, float b) {
    unsigned int r;
    asm volatile("v_cvt_pk_bf16_f32 %0, %1, %2" : "=v"(r) : "v"(a), "v"(b));
    return r;
}

// ---------- single fused kernel (R13 green state, exact revert) ----------
// grid 512 = (b, 8-m-group) XCD-swizzled; 512 threads = 8 waves; 2 blocks/CU.
// phase 0 (parallel): wave 0 builds G=[ReU;ImU] via basis-vector ladder;
//   waves 1..7 stage x[b,:,m0:m0+8] -> LDS as bf16 (cvtpk t-pairs).
// phase 1 (enc): wave w = row m=w; 4 tiles of 32 patches; per tile 2x
//   mfma_32x32x16 (Gh.vh + Gl.vh) -> D[32 G-rows][32 patches];
//   lane holds Re/Im for 8 k's of ONE patch -> p_i = D[i]^2+D[i+8]^2;
//   masked sums via 4 shfl_xor(32); z -> enc LDS ushort4.
// phase 2 (head): waves 0..5 one 16-col tile each (verified R6 mapping);
//   hw converted via cvtpk; SINGLE accumulator (dual-acc failed R14/R15 —
//   unexplained, do not reintroduce); D rows 8..15 discarded (kg<2 stores).
__global__ __launch_bounds__(512) void qml_one(
    const float* __restrict__ x,     // [B, L, M]
    const float* __restrict__ w,     // [2, 4, 3]
    const float* __restrict__ hw,    // [PRED, NCOLS] f32
    const float* __restrict__ hb,    // [PRED]
    float* __restrict__ out)         // [B, PRED, M]
{
    __shared__ float G[32 * 16];                    // [ReU; ImU], row r, col j
    __shared__ unsigned short xh[MG][XROW];         // 8.25 KB
    __shared__ unsigned short enc[MG][ELD];         // 8.1 KB

    const int tid  = threadIdx.x;
    const int lane = tid & 63;
    const int wv   = tid >> 6;          // wave 0..7

    // XCD swizzle: all 8 m-groups of batch b land on the same XCD (L2 shares x[b])
    const int idx = blockIdx.x;
    const int b   = ((idx >> 6) << 3) | (idx & 7);
    const int m0  = ((idx >> 3) & 7) * MG;

    if (wv == 0) {
        // ---- wave 0: gates in regs, shfl broadcast, basis-vector ladder ----
        float my[8];
        {
            const int  g      = lane & 7;
            const float phi   = w[g * 3 + 0];
            const float theta = w[g * 3 + 1];
            const float omega = w[g * 3 + 2];
            const float c  = cosf(0.5f * theta), s  = sinf(0.5f * theta);
            const float hf = 0.5f * (phi + omega), df = 0.5f * (phi - omega);
            const float ch = cosf(hf), sh = sinf(hf);
            const float cd = cosf(df), sd = sinf(df);
            my[0] =  ch * c;  my[1] = -sh * c;   // U00 = e^{-i hf} c
            my[2] = -cd * s;  my[3] = -sd * s;   // U01 = -e^{+i df} s
            my[4] =  cd * s;  my[5] = -sd * s;   // U10 = e^{-i df} s
            my[6] =  ch * c;  my[7] =  sh * c;   // U11 = e^{+i hf} c
        }
        float re[16], im[16];
        #pragma unroll
        for (int k = 0; k < 16; ++k) { re[k] = (k == (lane & 15)) ? 1.f : 0.f; im[k] = 0.f; }
        #pragma unroll
        for (int l = 0; l < 2; ++l) {
            #pragma unroll
            for (int qq = 0; qq < 4; ++qq) {
                const int g = l * 4 + qq;
                const float u00r = __shfl(my[0], g), u00i = __shfl(my[1], g);
                const float u01r = __shfl(my[2], g), u01i = __shfl(my[3], g);
                const float u10r = __shfl(my[4], g), u10i = __shfl(my[5], g);
                const float u11r = __shfl(my[6], g), u11i = __shfl(my[7], g);
                const int bit = 8 >> qq;
                #pragma unroll
                for (int k = 0; k < 16; ++k) {
                    if (k & bit) continue;
                    const int k1 = k | bit;
                    const float a0r = re[k],  a0i = im[k];
                    const float a1r = re[k1], a1i = im[k1];
                    re[k]  = u00r * a0r - u00i * a0i + u01r * a1r - u01i * a1i;
                    im[k]  = u00r * a0i + u00i * a0r + u01r * a1i + u01i * a1r;
                    re[k1] = u10r * a0r - u10i * a0i + u11r * a1r - u11i * a1i;
                    im[k1] = u10r * a0i + u10i * a0r + u11r * a1i + u11i * a1r;
                }
            }
            const int r = (l % 3) + 1;
            #pragma unroll
            for (int i = 0; i < 4; ++i) {
                const int cb = 8 >> i;
                const int tb = 8 >> ((i + r) & 3);
                #pragma unroll
                for (int k = 0; k < 16; ++k) {
                    if ((k & cb) && !(k & tb)) {
                        const int k1 = k | tb;
                        float t;
                        t = re[k]; re[k] = re[k1]; re[k1] = t;
                        t = im[k]; im[k] = im[k1]; im[k1] = t;
                    }
                }
            }
        }
        if (lane < 16) {
            #pragma unroll
            for (int k = 0; k < 16; ++k) {
                G[k * 16 + lane]        = re[k];   // Re U rows 0..15
                G[(16 + k) * 16 + lane] = im[k];   // Im U rows 16..31
            }
        }
    } else {
        // ---- waves 1..7: stage x -> LDS bf16, t-pairs packed via cvtpk ----
        const float* xb = x + (size_t)b * SEQLEN * NFEAT + m0;
        unsigned int* xh32[8];
        #pragma unroll
        for (int c = 0; c < 8; ++c) {
            xh32[c] = reinterpret_cast<unsigned int*>(&xh[c][0]);
        }
        for (int u = tid - 64; u < XROW / 2; u += 448) {
            const int t = 2 * u;
            float4 a0, a1, b0, b1;
            if (t < SEQLEN) {
                const float* base = xb + (size_t)t * NFEAT;
                a0 = *reinterpret_cast<const float4*>(base);
                a1 = *reinterpret_cast<const float4*>(base + 4);
                b0 = *reinterpret_cast<const float4*>(base + NFEAT);
                b1 = *reinterpret_cast<const float4*>(base + NFEAT + 4);
            } else {
                a0 = make_float4(0.f, 0.f, 0.f, 0.f);
                a1 = a0; b0 = a0; b1 = a0;
            }
            const float av[8] = {a0.x, a0.y, a0.z, a0.w, a1.x, a1.y, a1.z, a1.w};
            const float bv[8] = {b0.x, b0.y, b0.z, b0.w, b1.x, b1.y, b1.z, b1.w};
            #pragma unroll
            for (int c = 0; c < 8; ++c) {
                xh32[c][u] = cvtpk(av[c], bv[c]);
            }
        }
    }
    __syncthreads();

    // ---- phase 1: encoder via 32x32x16 MFMA; wave wv owns row m = wv ----
    {
        const int m  = wv;
        const int pl = lane & 31;           // patch-in-tile (D col)
        const int hi = lane >> 5;           // K-half / G-row-half select
        const int j0 = hi * 8;

        // A-fragments: A[r][k] with r=lane&31, k=j0+c (hi/lo split of G)
        short8 gah, gal;
        {
            const int r = lane & 31;
            #pragma unroll
            for (int c = 0; c < 8; ++c) {
                const float g = G[r * 16 + j0 + c];
                const unsigned short h = f2bf(g);
                gah[c] = (short)h;
                gal[c] = (short)f2bf(g - bf2f(h));
            }
        }

        const unsigned short* xhr = &xh[m][0];
        #pragma unroll 1
        for (int nt = 0; nt < 4; ++nt) {
            const int p = nt * 32 + pl;     // patch 0..127
            // B-fragment: col p, K rows j0..j0+7 -> v[4p + j0 .. +7]
            const int base = 4 * p + j0;
            const short4v h0 = *reinterpret_cast<const short4v*>(xhr + base);
            const short4v h1 = *reinterpret_cast<const short4v*>(xhr + base + 4);
            short8 bh;
            #pragma unroll
            for (int c = 0; c < 4; ++c) {
                bh[c] = h0[c]; bh[c + 4] = h1[c];
            }

            f32x16 D = {0.f, 0.f, 0.f, 0.f, 0.f, 0.f, 0.f, 0.f,
                        0.f, 0.f, 0.f, 0.f, 0.f, 0.f, 0.f, 0.f};
            D = __builtin_amdgcn_mfma_f32_32x32x16_bf16(gah, bh, D, 0, 0, 0);
            D = __builtin_amdgcn_mfma_f32_32x32x16_bf16(gal, bh, D, 0, 0, 0);

            // lane holds Re (regs 0..7) and Im (regs 8..15) for 8 k's of patch p
            float pi[8];
            #pragma unroll
            for (int i = 0; i < 8; ++i) pi[i] = D[i] * D[i] + D[i + 8] * D[i + 8];

            const float sa_p = ((pi[0] + pi[1]) + (pi[2] + pi[3]))
                             + ((pi[4] + pi[5]) + (pi[6] + pi[7]));
            const float s0_p = (pi[4] + pi[5]) + (pi[6] + pi[7]);   // k&8 <-> i>=4
            const float s2_p = (pi[2] + pi[3]) + (pi[6] + pi[7]);   // k&2 <-> i&2
            const float s3_p = (pi[1] + pi[3]) + (pi[5] + pi[7]);   // k&1 <-> i&1

            const float o_sa = __shfl_xor(sa_p, 32);
            const float o_s0 = __shfl_xor(s0_p, 32);
            const float o_s2 = __shfl_xor(s2_p, 32);
            const float o_s3 = __shfl_xor(s3_p, 32);

            const float sa = sa_p + o_sa;
            const float s0 = s0_p + o_s0;
            const float s1 = hi ? sa_p : o_sa;                      // k&4 <-> hi
            const float s2 = s2_p + o_s2;
            const float s3 = s3_p + o_s3;

            const float t  = -2.f / sa;                             // sa > 0 for p < NPATCH
            ushort4v zv;
            if (p < NPATCH) {
                zv[0] = f2bf(fmaf(t, s0, 1.f));
                zv[1] = f2bf(fmaf(t, s1, 1.f));
                zv[2] = f2bf(fmaf(t, s2, 1.f));
                zv[3] = f2bf(fmaf(t, s3, 1.f));
            } else {
                zv[0] = 0; zv[1] = 0; zv[2] = 0; zv[3] = 0;        // keep head MFMA NaN-free
            }
            if (hi == 0) {
                *reinterpret_cast<ushort4v*>(&enc[m][4 * p]) = zv;
            }
        }
    }
    __syncthreads();

    // ---- phase 2: head GEMM; waves 0..5 = 16-col tiles (R6-verified) ----
    if (wv < 6) {
        const int lr = lane & 15;
        const int kg = lane >> 4;
        const int o  = wv * 16 + lr;                // output column
        const float* hwrow = hw + (size_t)o * NCOLS;
        const unsigned short* erow = &enc[lr & 7][0];   // rows 8..15 duplicated, discarded

        f32x4 acc = {0.f, 0.f, 0.f, 0.f};
        #pragma unroll 4
        for (int kc = 0; kc < 15; ++kc) {
            const int k0 = kc * 32 + kg * 8;
            const short8 e  = *reinterpret_cast<const short8*>(erow + k0);
            const float4 w0 = *reinterpret_cast<const float4*>(hwrow + k0);
            const float4 w1 = *reinterpret_cast<const float4*>(hwrow + k0 + 4);
            union { unsigned int u[4]; short8 s; } wf;
            wf.u[0] = cvtpk(w0.x, w0.y);
            wf.u[1] = cvtpk(w0.z, w0.w);
            wf.u[2] = cvtpk(w1.x, w1.y);
            wf.u[3] = cvtpk(w1.z, w1.w);
            acc = __builtin_amdgcn_mfma_f32_16x16x32_bf16(e, wf.s, acc, 0, 0, 0);
        }
        {   // kc = 15 peel: k in [480, 512); zero-pad k >= 500
            const int k0 = 480 + kg * 8;
            const short8 e = *reinterpret_cast<const short8*>(erow + k0);
            short8 wf;
            #pragma unroll
            for (int c = 0; c < 8; ++c) {
                const int k = k0 + c;
                wf[c] = (k < NCOLS) ? (short)f2bf(hwrow[k]) : (short)0;
            }
            acc = __builtin_amdgcn_mfma_f32_16x16x32_bf16(e, wf, acc, 0, 0, 0);
        }

        if (kg < 2) {                               // D rows 0..7 valid (MG=8)
            const float bias = hb[o];
            #pragma unroll
            for (int j = 0; j < 4; ++j) {
                const int m = m0 + 4 * kg + j;
                out[((size_t)b * PREDLEN + o) * NFEAT + m] = acc[j] + bias;
            }
        }
    }
}

extern "C" void kernel_launch(void* const* d_in, const int* in_sizes, int n_in,
                              void* d_out, int out_size, void* d_ws, size_t ws_size,
                              hipStream_t stream) {
    const float* x  = (const float*)d_in[0];   // [64, 512, 64]
    const float* w  = (const float*)d_in[1];   // [2, 4, 3]
    const float* hw = (const float*)d_in[2];   // [96, 500]
    const float* hb = (const float*)d_in[3];   // [96]
    float* out = (float*)d_out;                // [64, 96, 64]

    (void)d_ws; (void)ws_size; (void)in_sizes; (void)n_in; (void)out_size;
    qml_one<<<dim3(BATCH * (NFEAT / MG)), dim3(512), 0, stream>>>(x, w, hw, hb, out);
}

// Round 18
// 23.573 us; speedup vs baseline: 1.0069x; 1.0069x over previous
//
#include <hip/hip_runtime.h>
#include <cmath>

// Problem constants
#define BATCH 64
#define SEQLEN 512
#define NFEAT 64
#define NPATCH 125
#define PREDLEN 96
#define NCOLS 500

#define MG 8         // m-rows per block (R9 sweet spot)
#define XROW 528     // xh row length (ushorts): 512 + 16 zero tail
#define ELD 520      // enc LDS row stride (ushorts)

typedef __attribute__((ext_vector_type(8))) short short8;     // 8 bf16 (4 VGPR)
typedef __attribute__((ext_vector_type(4))) short short4v;    // 4 bf16
typedef __attribute__((ext_vector_type(4))) unsigned short ushort4v;
typedef __attribute__((ext_vector_type(4))) float f32x4;      // 16x16 acc
typedef __attribute__((ext_vector_type(16))) float f32x16;    // 32x32 acc

__device__ __forceinline__ unsigned short f2bf(float f) {   // f32 -> bf16 RNE
    unsigned int u = __float_as_uint(f);
    u += 0x7FFFu + ((u >> 16) & 1u);
    return (unsigned short)(u >> 16);
}
__device__ __forceinline__ float bf2f(unsigned short h) {
    return __uint_as_float(((unsigned int)h) << 16);
}
// 2x f32 -> packed 2x bf16 (RNE): d.lo = bf16(a), d.hi = bf16(b)
__device__ __forceinline__ unsigned int cvtpk(float a, float b) {
    unsigned int r;
    asm volatile("v_cvt_pk_bf16_f32 %0, %1, %2" : "=v"(r) : "v"(a), "v"(b));
    return r;
}

// ---------- single fused kernel (R13/R16 green state, exact revert) ----------
// grid 512 = (b, 8-m-group) XCD-swizzled; 512 threads = 8 waves; 2 blocks/CU.
// DO-NOT-TOUCH notes from failed experiments on this kernel shape:
//  - dual MFMA accumulators w/ conditional select: FAILED (R14/R15)
//  - enc nt-loop unroll 2: FAILED (R15)
//  - __launch_bounds__(512,4) reg-cap: FAILED (R17)
//  All three perturb register allocation and corrupt numerics (absmax
//  0.07-0.125) — latent codegen hazard; keep this exact green codegen.
// phase 0 (parallel): wave 0 builds G=[ReU;ImU] via basis-vector ladder;
//   waves 1..7 stage x[b,:,m0:m0+8] -> LDS as bf16 (cvtpk t-pairs).
// phase 1 (enc): wave w = row m=w; 4 tiles of 32 patches; per tile 2x
//   mfma_32x32x16 (Gh.vh + Gl.vh); masked sums via shfl_xor(32); z -> LDS.
// phase 2 (head): waves 0..5 one 16-col tile each (verified R6 mapping);
//   hw converted via cvtpk; single accumulator; kg<2 stores only.
__global__ __launch_bounds__(512) void qml_one(
    const float* __restrict__ x,     // [B, L, M]
    const float* __restrict__ w,     // [2, 4, 3]
    const float* __restrict__ hw,    // [PRED, NCOLS] f32
    const float* __restrict__ hb,    // [PRED]
    float* __restrict__ out)         // [B, PRED, M]
{
    __shared__ float G[32 * 16];                    // [ReU; ImU], row r, col j
    __shared__ unsigned short xh[MG][XROW];         // 8.25 KB
    __shared__ unsigned short enc[MG][ELD];         // 8.1 KB

    const int tid  = threadIdx.x;
    const int lane = tid & 63;
    const int wv   = tid >> 6;          // wave 0..7

    // XCD swizzle: all 8 m-groups of batch b land on the same XCD (L2 shares x[b])
    const int idx = blockIdx.x;
    const int b   = ((idx >> 6) << 3) | (idx & 7);
    const int m0  = ((idx >> 3) & 7) * MG;

    if (wv == 0) {
        // ---- wave 0: gates in regs, shfl broadcast, basis-vector ladder ----
        float my[8];
        {
            const int  g      = lane & 7;
            const float phi   = w[g * 3 + 0];
            const float theta = w[g * 3 + 1];
            const float omega = w[g * 3 + 2];
            const float c  = cosf(0.5f * theta), s  = sinf(0.5f * theta);
            const float hf = 0.5f * (phi + omega), df = 0.5f * (phi - omega);
            const float ch = cosf(hf), sh = sinf(hf);
            const float cd = cosf(df), sd = sinf(df);
            my[0] =  ch * c;  my[1] = -sh * c;   // U00 = e^{-i hf} c
            my[2] = -cd * s;  my[3] = -sd * s;   // U01 = -e^{+i df} s
            my[4] =  cd * s;  my[5] = -sd * s;   // U10 = e^{-i df} s
            my[6] =  ch * c;  my[7] =  sh * c;   // U11 = e^{+i hf} c
        }
        float re[16], im[16];
        #pragma unroll
        for (int k = 0; k < 16; ++k) { re[k] = (k == (lane & 15)) ? 1.f : 0.f; im[k] = 0.f; }
        #pragma unroll
        for (int l = 0; l < 2; ++l) {
            #pragma unroll
            for (int qq = 0; qq < 4; ++qq) {
                const int g = l * 4 + qq;
                const float u00r = __shfl(my[0], g), u00i = __shfl(my[1], g);
                const float u01r = __shfl(my[2], g), u01i = __shfl(my[3], g);
                const float u10r = __shfl(my[4], g), u10i = __shfl(my[5], g);
                const float u11r = __shfl(my[6], g), u11i = __shfl(my[7], g);
                const int bit = 8 >> qq;
                #pragma unroll
                for (int k = 0; k < 16; ++k) {
                    if (k & bit) continue;
                    const int k1 = k | bit;
                    const float a0r = re[k],  a0i = im[k];
                    const float a1r = re[k1], a1i = im[k1];
                    re[k]  = u00r * a0r - u00i * a0i + u01r * a1r - u01i * a1i;
                    im[k]  = u00r * a0i + u00i * a0r + u01r * a1i + u01i * a1r;
                    re[k1] = u10r * a0r - u10i * a0i + u11r * a1r - u11i * a1i;
                    im[k1] = u10r * a0i + u10i * a0r + u11r * a1i + u11i * a1r;
                }
            }
            const int r = (l % 3) + 1;
            #pragma unroll
            for (int i = 0; i < 4; ++i) {
                const int cb = 8 >> i;
                const int tb = 8 >> ((i + r) & 3);
                #pragma unroll
                for (int k = 0; k < 16; ++k) {
                    if ((k & cb) && !(k & tb)) {
                        const int k1 = k | tb;
                        float t;
                        t = re[k]; re[k] = re[k1]; re[k1] = t;
                        t = im[k]; im[k] = im[k1]; im[k1] = t;
                    }
                }
            }
        }
        if (lane < 16) {
            #pragma unroll
            for (int k = 0; k < 16; ++k) {
                G[k * 16 + lane]        = re[k];   // Re U rows 0..15
                G[(16 + k) * 16 + lane] = im[k];   // Im U rows 16..31
            }
        }
    } else {
        // ---- waves 1..7: stage x -> LDS bf16, t-pairs packed via cvtpk ----
        const float* xb = x + (size_t)b * SEQLEN * NFEAT + m0;
        unsigned int* xh32[8];
        #pragma unroll
        for (int c = 0; c < 8; ++c) {
            xh32[c] = reinterpret_cast<unsigned int*>(&xh[c][0]);
        }
        for (int u = tid - 64; u < XROW / 2; u += 448) {
            const int t = 2 * u;
            float4 a0, a1, b0, b1;
            if (t < SEQLEN) {
                const float* base = xb + (size_t)t * NFEAT;
                a0 = *reinterpret_cast<const float4*>(base);
                a1 = *reinterpret_cast<const float4*>(base + 4);
                b0 = *reinterpret_cast<const float4*>(base + NFEAT);
                b1 = *reinterpret_cast<const float4*>(base + NFEAT + 4);
            } else {
                a0 = make_float4(0.f, 0.f, 0.f, 0.f);
                a1 = a0; b0 = a0; b1 = a0;
            }
            const float av[8] = {a0.x, a0.y, a0.z, a0.w, a1.x, a1.y, a1.z, a1.w};
            const float bv[8] = {b0.x, b0.y, b0.z, b0.w, b1.x, b1.y, b1.z, b1.w};
            #pragma unroll
            for (int c = 0; c < 8; ++c) {
                xh32[c][u] = cvtpk(av[c], bv[c]);
            }
        }
    }
    __syncthreads();

    // ---- phase 1: encoder via 32x32x16 MFMA; wave wv owns row m = wv ----
    {
        const int m  = wv;
        const int pl = lane & 31;           // patch-in-tile (D col)
        const int hi = lane >> 5;           // K-half / G-row-half select
        const int j0 = hi * 8;

        // A-fragments: A[r][k] with r=lane&31, k=j0+c (hi/lo split of G)
        short8 gah, gal;
        {
            const int r = lane & 31;
            #pragma unroll
            for (int c = 0; c < 8; ++c) {
                const float g = G[r * 16 + j0 + c];
                const unsigned short h = f2bf(g);
                gah[c] = (short)h;
                gal[c] = (short)f2bf(g - bf2f(h));
            }
        }

        const unsigned short* xhr = &xh[m][0];
        #pragma unroll 1
        for (int nt = 0; nt < 4; ++nt) {
            const int p = nt * 32 + pl;     // patch 0..127
            // B-fragment: col p, K rows j0..j0+7 -> v[4p + j0 .. +7]
            const int base = 4 * p + j0;
            const short4v h0 = *reinterpret_cast<const short4v*>(xhr + base);
            const short4v h1 = *reinterpret_cast<const short4v*>(xhr + base + 4);
            short8 bh;
            #pragma unroll
            for (int c = 0; c < 4; ++c) {
                bh[c] = h0[c]; bh[c + 4] = h1[c];
            }

            f32x16 D = {0.f, 0.f, 0.f, 0.f, 0.f, 0.f, 0.f, 0.f,
                        0.f, 0.f, 0.f, 0.f, 0.f, 0.f, 0.f, 0.f};
            D = __builtin_amdgcn_mfma_f32_32x32x16_bf16(gah, bh, D, 0, 0, 0);
            D = __builtin_amdgcn_mfma_f32_32x32x16_bf16(gal, bh, D, 0, 0, 0);

            // lane holds Re (regs 0..7) and Im (regs 8..15) for 8 k's of patch p
            float pi[8];
            #pragma unroll
            for (int i = 0; i < 8; ++i) pi[i] = D[i] * D[i] + D[i + 8] * D[i + 8];

            const float sa_p = ((pi[0] + pi[1]) + (pi[2] + pi[3]))
                             + ((pi[4] + pi[5]) + (pi[6] + pi[7]));
            const float s0_p = (pi[4] + pi[5]) + (pi[6] + pi[7]);   // k&8 <-> i>=4
            const float s2_p = (pi[2] + pi[3]) + (pi[6] + pi[7]);   // k&2 <-> i&2
            const float s3_p = (pi[1] + pi[3]) + (pi[5] + pi[7]);   // k&1 <-> i&1

            const float o_sa = __shfl_xor(sa_p, 32);
            const float o_s0 = __shfl_xor(s0_p, 32);
            const float o_s2 = __shfl_xor(s2_p, 32);
            const float o_s3 = __shfl_xor(s3_p, 32);

            const float sa = sa_p + o_sa;
            const float s0 = s0_p + o_s0;
            const float s1 = hi ? sa_p : o_sa;                      // k&4 <-> hi
            const float s2 = s2_p + o_s2;
            const float s3 = s3_p + o_s3;

            const float t  = -2.f / sa;                             // sa > 0 for p < NPATCH
            ushort4v zv;
            if (p < NPATCH) {
                zv[0] = f2bf(fmaf(t, s0, 1.f));
                zv[1] = f2bf(fmaf(t, s1, 1.f));
                zv[2] = f2bf(fmaf(t, s2, 1.f));
                zv[3] = f2bf(fmaf(t, s3, 1.f));
            } else {
                zv[0] = 0; zv[1] = 0; zv[2] = 0; zv[3] = 0;        // keep head MFMA NaN-free
            }
            if (hi == 0) {
                *reinterpret_cast<ushort4v*>(&enc[m][4 * p]) = zv;
            }
        }
    }
    __syncthreads();

    // ---- phase 2: head GEMM; waves 0..5 = 16-col tiles (R6-verified) ----
    if (wv < 6) {
        const int lr = lane & 15;
        const int kg = lane >> 4;
        const int o  = wv * 16 + lr;                // output column
        const float* hwrow = hw + (size_t)o * NCOLS;
        const unsigned short* erow = &enc[lr & 7][0];   // rows 8..15 duplicated, discarded

        f32x4 acc = {0.f, 0.f, 0.f, 0.f};
        #pragma unroll 4
        for (int kc = 0; kc < 15; ++kc) {
            const int k0 = kc * 32 + kg * 8;
            const short8 e  = *reinterpret_cast<const short8*>(erow + k0);
            const float4 w0 = *reinterpret_cast<const float4*>(hwrow + k0);
            const float4 w1 = *reinterpret_cast<const float4*>(hwrow + k0 + 4);
            union { unsigned int u[4]; short8 s; } wf;
            wf.u[0] = cvtpk(w0.x, w0.y);
            wf.u[1] = cvtpk(w0.z, w0.w);
            wf.u[2] = cvtpk(w1.x, w1.y);
            wf.u[3] = cvtpk(w1.z, w1.w);
            acc = __builtin_amdgcn_mfma_f32_16x16x32_bf16(e, wf.s, acc, 0, 0, 0);
        }
        {   // kc = 15 peel: k in [480, 512); zero-pad k >= 500
            const int k0 = 480 + kg * 8;
            const short8 e = *reinterpret_cast<const short8*>(erow + k0);
            short8 wf;
            #pragma unroll
            for (int c = 0; c < 8; ++c) {
                const int k = k0 + c;
                wf[c] = (k < NCOLS) ? (short)f2bf(hwrow[k]) : (short)0;
            }
            acc = __builtin_amdgcn_mfma_f32_16x16x32_bf16(e, wf, acc, 0, 0, 0);
        }

        if (kg < 2) {                               // D rows 0..7 valid (MG=8)
            const float bias = hb[o];
            #pragma unroll
            for (int j = 0; j < 4; ++j) {
                const int m = m0 + 4 * kg + j;
                out[((size_t)b * PREDLEN + o) * NFEAT + m] = acc[j] + bias;
            }
        }
    }
}

extern "C" void kernel_launch(void* const* d_in, const int* in_sizes, int n_in,
                              void* d_out, int out_size, void* d_ws, size_t ws_size,
                              hipStream_t stream) {
    const float* x  = (const float*)d_in[0];   // [64, 512, 64]
    const float* w  = (const float*)d_in[1];   // [2, 4, 3]
    const float* hw = (const float*)d_in[2];   // [96, 500]
    const float* hb = (const float*)d_in[3];   // [96]
    float* out = (float*)d_out;                // [64, 96, 64]

    (void)d_ws; (void)ws_size; (void)in_sizes; (void)n_in; (void)out_size;
    qml_one<<<dim3(BATCH * (NFEAT / MG)), dim3(512), 0, stream>>>(x, w, hw, hb, out);
}